// Round 1
// baseline (1071.560 us; speedup 1.0000x reference)
//
#include <hip/hip_runtime.h>
#include <math.h>

__device__ __forceinline__ float wsum(float v){
  #pragma unroll
  for (int o=32;o;o>>=1) v += __shfl_xor(v,o);
  return v;
}
__device__ __forceinline__ float wmax(float v){
  #pragma unroll
  for (int o=32;o;o>>=1) v = fmaxf(v, __shfl_xor(v,o));
  return v;
}

// out[n,64] = x[n,K] @ W[K,64] + b[64]
__global__ void k_embed(const float* __restrict__ x, const float* __restrict__ W,
                        const float* __restrict__ b, float* __restrict__ out,
                        int n, int K){
  int idx = blockIdx.x*blockDim.x + threadIdx.x;
  if (idx >= n*64) return;
  int node = idx >> 6, f = idx & 63;
  float acc = b[f];
  for (int k=0;k<K;++k) acc = fmaf(x[node*K+k], W[k*64+f], acc);
  out[idx] = acc;
}

// escal[l] = W_edge_row . (lin_edge_l @ att_e_l); escal[3+l] = b_edge . (...)
__global__ void k_edge_scalars(const float* __restrict__ lin_edge, // [3,64,64]
                               const float* __restrict__ att_e,   // [3,64]
                               const float* __restrict__ Wrow,    // [64]
                               const float* __restrict__ bemb,    // [64]
                               float* __restrict__ escal){
  int l = threadIdx.x >> 6, j = threadIdx.x & 63;
  float v = 0.f;
  for (int k=0;k<64;++k) v = fmaf(lin_edge[l*4096 + j*64 + k], att_e[l*64+k], v);
  float sv = wsum(Wrow[j]*v);
  float ov = wsum(bemb[j]*v);
  if (j==0){ escal[l]=sv; escal[3+l]=ov; }
}

__global__ void k_count(const int* __restrict__ dst, int* __restrict__ deg, int e){
  int i = blockIdx.x*blockDim.x + threadIdx.x;
  if (i<e) atomicAdd(&deg[dst[i]], 1);
}

__global__ void k_scan1(const int* __restrict__ deg, int* __restrict__ row1,
                        int* __restrict__ part, int n){
  __shared__ int sm[256];
  int i = blockIdx.x*256 + threadIdx.x;
  int v = (i<n) ? deg[i] : 0;
  sm[threadIdx.x] = v; __syncthreads();
  for (int o=1;o<256;o<<=1){
    int t = (threadIdx.x>= (unsigned)o) ? sm[threadIdx.x-o] : 0;
    __syncthreads();
    sm[threadIdx.x] += t; __syncthreads();
  }
  if (i<n) row1[i] = sm[threadIdx.x];
  if (threadIdx.x==255) part[blockIdx.x] = sm[255];
}

__global__ void k_scan2(int* __restrict__ part, int np){
  __shared__ int sm[1024];
  int t = threadIdx.x;
  sm[t] = (t<np) ? part[t] : 0; __syncthreads();
  for (int o=1;o<1024;o<<=1){
    int v = (t>=o) ? sm[t-o] : 0;
    __syncthreads();
    sm[t] += v; __syncthreads();
  }
  if (t<np) part[t] = (t==0) ? 0 : sm[t-1];
}

__global__ void k_scan3(int* __restrict__ rowptr, const int* __restrict__ part, int n){
  int i = blockIdx.x*256 + threadIdx.x;
  if (i<n) rowptr[i+1] += part[blockIdx.x];
  if (i==0) rowptr[0]=0;
}

__global__ void k_scan_single(const int* __restrict__ deg, int* __restrict__ rowptr, int n){
  __shared__ int sm[1024];
  int t = threadIdx.x;
  sm[t] = (t<n) ? deg[t] : 0; __syncthreads();
  for (int o=1;o<blockDim.x;o<<=1){
    int v = (t>=o)?sm[t-o]:0; __syncthreads();
    sm[t]+=v; __syncthreads();
  }
  if (t<n) rowptr[t+1]=sm[t];
  if (t==0) rowptr[0]=0;
}

__global__ void k_fill(const int* __restrict__ src, const int* __restrict__ dst,
                       const float* __restrict__ attr, const int* __restrict__ rowptr,
                       int* __restrict__ fillc, int* __restrict__ slot_src,
                       float* __restrict__ slot_attr, int e){
  int i = blockIdx.x*blockDim.x + threadIdx.x;
  if (i>=e) return;
  int d = dst[i];
  int pos = rowptr[d] + atomicAdd(&fillc[d], 1);
  slot_src[pos] = src[i];
  if (attr) slot_attr[pos] = attr[i];
}

// hs[n,64] = h[n,64] @ W[64,64]; as_[i]=hs[i].att_s; ad_[i]=hs[i].att_d
__global__ __launch_bounds__(256) void k_gemm64(
    const float* __restrict__ h, const float* __restrict__ W,
    const float* __restrict__ att_s, const float* __restrict__ att_d,
    float* __restrict__ hs, float* __restrict__ as_, float* __restrict__ ad_, int n){
  __shared__ float Ws[64*64];
  __shared__ float hT[64][68];   // +4 pad breaks transpose-write conflicts
  int t = threadIdx.x;
  int n0 = blockIdx.x * 64;
  #pragma unroll
  for (int i=t;i<4096;i+=256) Ws[i] = W[i];
  for (int i=t;i<1024;i+=256){
    int node = i >> 4, k4 = (i & 15) << 2;
    int gn = n0 + node;
    float4 v = (gn < n) ? *(const float4*)&h[(size_t)gn*64 + k4] : make_float4(0,0,0,0);
    hT[k4+0][node]=v.x; hT[k4+1][node]=v.y; hT[k4+2][node]=v.z; hT[k4+3][node]=v.w;
  }
  __syncthreads();
  int tx = t & 15, ty = t >> 4;   // tx: feature quad, ty: node quad
  int f4 = tx*4;
  float acc[4][4] = {};
  for (int k=0;k<64;++k){
    float4 wv = *(const float4*)&Ws[k*64 + f4];
    float4 hv = *(const float4*)&hT[k][ty*4];
    float hvv[4] = {hv.x,hv.y,hv.z,hv.w};
    float wvv[4] = {wv.x,wv.y,wv.z,wv.w};
    #pragma unroll
    for (int i=0;i<4;++i)
      #pragma unroll
      for (int j=0;j<4;++j)
        acc[i][j] = fmaf(hvv[i], wvv[j], acc[i][j]);
  }
  float4 s4 = *(const float4*)&att_s[f4];
  float4 d4 = *(const float4*)&att_d[f4];
  #pragma unroll
  for (int i=0;i<4;++i){
    int gn = n0 + ty*4 + i;
    if (gn < n){
      *(float4*)&hs[(size_t)gn*64 + f4] = make_float4(acc[i][0],acc[i][1],acc[i][2],acc[i][3]);
      float sv = acc[i][0]*s4.x + acc[i][1]*s4.y + acc[i][2]*s4.z + acc[i][3]*s4.w;
      float dv = acc[i][0]*d4.x + acc[i][1]*d4.y + acc[i][2]*d4.z + acc[i][3]*d4.w;
      #pragma unroll
      for (int o=8;o;o>>=1){ sv += __shfl_xor(sv,o); dv += __shfl_xor(dv,o); }
      if (tx==0){ as_[gn]=sv; ad_[gn]=dv; }
    }
  }
}

// one wave per dst node: alpha -> max -> exp/sum -> weighted gather of hs[src]
__global__ void k_gat_agg(const int* __restrict__ rowptr, const int* __restrict__ slot_src,
                          const float* __restrict__ slot_attr, float* __restrict__ alpha_ws,
                          const float* __restrict__ as_, const float* __restrict__ ad_,
                          const float* __restrict__ hs, const float* __restrict__ bias,
                          const float* __restrict__ escal, int l,
                          float* __restrict__ out, int n, int do_relu){
  int wv = threadIdx.x >> 6, lane = threadIdx.x & 63;
  int node = blockIdx.x*4 + wv;
  if (node >= n) return;
  int beg = rowptr[node], end = rowptr[node+1];
  float bi = bias[lane];
  if (end == beg){
    float r = bi;
    if (do_relu) r = fmaxf(r, 0.f);
    out[(size_t)node*64+lane] = r;
    return;
  }
  float se = 0.f, oe = 0.f;
  if (escal){ se = escal[l]; oe = escal[3+l]; }
  float adn = ad_[node];
  float m = -1e30f;
  for (int k = beg + lane; k < end; k += 64){
    int s = slot_src[k];
    float a = as_[s] + adn;
    if (slot_attr) a = fmaf(slot_attr[k], se, a) + oe;
    a = (a >= 0.f) ? a : 0.2f*a;   // leaky_relu 0.2
    alpha_ws[k] = a;
    m = fmaxf(m, a);
  }
  m = wmax(m);
  float acc = 0.f, sum = 0.f;
  for (int base = beg; base < end; base += 64){
    int k = base + lane;
    float p = 0.f; int s = 0;
    if (k < end){ s = slot_src[k]; p = __expf(alpha_ws[k] - m); }
    sum += p;
    int cnt = min(64, end - base);
    for (int j=0;j<cnt;++j){
      int   sj = __shfl(s, j);
      float pj = __shfl(p, j);
      acc = fmaf(hs[(size_t)sj*64 + lane], pj, acc);
    }
  }
  sum = wsum(sum);
  float r = acc / sum + bi;
  if (do_relu) r = fmaxf(r, 0.f);
  out[(size_t)node*64 + lane] = r;
}

// ad_w[w] = (h_w[w] @ wc_lin) . att_d
__global__ void k_well_ad(const float* __restrict__ hw, const float* __restrict__ W,
                          const float* __restrict__ att_d, float* __restrict__ ad_w, int n){
  int wv = threadIdx.x>>6, lane = threadIdx.x&63;
  int w = blockIdx.x*4 + wv;
  if (w>=n) return;
  float acc=0.f;
  for (int k=0;k<64;++k) acc = fmaf(hw[w*64+k], W[k*64+lane], acc);
  float v = wsum(acc * att_d[lane]);
  if (lane==0) ad_w[w]=v;
}

__global__ __launch_bounds__(128) void k_mlp(const float* __restrict__ h_well,
    const float* __restrict__ W1, const float* __restrict__ b1,
    const float* __restrict__ W2, const float* __restrict__ b2,
    float* __restrict__ out, int n){
  __shared__ float hr[64]; __shared__ float h1[64];
  int w = blockIdx.x, t = threadIdx.x;
  if (t<64) hr[t] = h_well[w*64+t];
  __syncthreads();
  if (t<64){
    float a = b1[t];
    for (int k=0;k<64;++k) a = fmaf(hr[k], W1[k*64+t], a);
    h1[t] = fmaxf(a, 0.f);
  }
  __syncthreads();
  if (t<75){
    float a = b2[t];
    for (int k=0;k<64;++k) a = fmaf(h1[k], W2[k*75+t], a);
    out[w*75+t] = a;
  }
}

extern "C" void kernel_launch(void* const* d_in, const int* in_sizes, int n_in,
                              void* d_out, int out_size, void* d_ws, size_t ws_size,
                              hipStream_t stream){
  const float* cell_x = (const float*)d_in[0];
  const float* well_x = (const float*)d_in[1];
  const float* eattr  = (const float*)d_in[2];
  const int*   cc_idx = (const int*)d_in[3];
  const int*   cw_idx = (const int*)d_in[4];
  const float* W_cell = (const float*)d_in[5];
  const float* b_cell = (const float*)d_in[6];
  const float* W_well = (const float*)d_in[7];
  const float* b_well = (const float*)d_in[8];
  const float* W_edge = (const float*)d_in[9];
  const float* b_edge = (const float*)d_in[10];
  const float* conv_lin = (const float*)d_in[11];
  const float* conv_lin_edge = (const float*)d_in[12];
  const float* att_src = (const float*)d_in[13];
  const float* att_dst = (const float*)d_in[14];
  const float* att_edge = (const float*)d_in[15];
  const float* conv_bias = (const float*)d_in[16];
  const float* wc_lin = (const float*)d_in[17];
  const float* wc_att_src = (const float*)d_in[18];
  const float* wc_att_dst = (const float*)d_in[19];
  const float* wc_bias = (const float*)d_in[20];
  const float* mlp_W1 = (const float*)d_in[21];
  const float* mlp_b1 = (const float*)d_in[22];
  const float* mlp_W2 = (const float*)d_in[23];
  const float* mlp_b2 = (const float*)d_in[24];

  int n_cell = in_sizes[0]/12;
  int n_well = in_sizes[1]/8;
  int e_cc = in_sizes[2];
  int e_cw = in_sizes[4]/2;

  const int* cc_src = cc_idx;
  const int* cc_dst = cc_idx + e_cc;
  const int* cw_src = cw_idx;
  const int* cw_dst = cw_idx + e_cw;

  char* p = (char*)d_ws;
  auto alloc = [&](size_t bytes)->void*{
    void* r = (void*)p;
    p += (bytes + 255) & ~(size_t)255;
    return r;
  };
  float* h_cur = (float*)alloc((size_t)n_cell*64*4);
  float* hs    = (float*)alloc((size_t)n_cell*64*4);
  float* as_   = (float*)alloc((size_t)n_cell*4);
  float* ad_   = (float*)alloc((size_t)n_cell*4);
  int* deg     = (int*)alloc((size_t)n_cell*4);
  int* fillc   = (int*)alloc((size_t)n_cell*4);
  int* rowptr  = (int*)alloc((size_t)(n_cell+1)*4);
  int* part    = (int*)alloc(1024*4);
  int* slot_src= (int*)alloc((size_t)e_cc*4);
  float* slot_attr = (float*)alloc((size_t)e_cc*4);
  float* alpha_ws  = (float*)alloc((size_t)e_cc*4);
  float* hw    = (float*)alloc((size_t)n_well*64*4);
  float* ad_w  = (float*)alloc((size_t)n_well*4);
  int* wdeg    = (int*)alloc((size_t)n_well*4);
  int* wfill   = (int*)alloc((size_t)n_well*4);
  int* wrowptr = (int*)alloc((size_t)(n_well+1)*4);
  int* wslot   = (int*)alloc((size_t)e_cw*4);
  float* walpha= (float*)alloc((size_t)e_cw*4);
  float* h_well= (float*)alloc((size_t)n_well*64*4);
  float* escal = (float*)alloc(64);

  hipMemsetAsync(deg, 0, (size_t)n_cell*4, stream);
  hipMemsetAsync(fillc, 0, (size_t)n_cell*4, stream);
  hipMemsetAsync(wdeg, 0, (size_t)n_well*4, stream);
  hipMemsetAsync(wfill, 0, (size_t)n_well*4, stream);

  // embeddings + edge scalars
  k_embed<<<(n_cell*64+255)/256, 256, 0, stream>>>(cell_x, W_cell, b_cell, h_cur, n_cell, 12);
  k_embed<<<(n_well*64+255)/256, 256, 0, stream>>>(well_x, W_well, b_well, hw, n_well, 8);
  k_edge_scalars<<<1, 192, 0, stream>>>(conv_lin_edge, att_edge, W_edge, b_edge, escal);

  // CSR (cells, by dst)
  k_count<<<(e_cc+255)/256, 256, 0, stream>>>(cc_dst, deg, e_cc);
  int nb = (n_cell+255)/256;
  k_scan1<<<nb, 256, 0, stream>>>(deg, rowptr+1, part, n_cell);
  k_scan2<<<1, 1024, 0, stream>>>(part, nb);
  k_scan3<<<nb, 256, 0, stream>>>(rowptr, part, n_cell);
  k_fill<<<(e_cc+255)/256, 256, 0, stream>>>(cc_src, cc_dst, eattr, rowptr, fillc, slot_src, slot_attr, e_cc);

  // CSR (wells)
  k_count<<<(e_cw+255)/256, 256, 0, stream>>>(cw_dst, wdeg, e_cw);
  k_scan_single<<<1, 512, 0, stream>>>(wdeg, wrowptr, n_well);
  k_fill<<<(e_cw+255)/256, 256, 0, stream>>>(cw_src, cw_dst, nullptr, wrowptr, wfill, wslot, nullptr, e_cw);

  // 3 GAT conv layers (cells)
  for (int l=0;l<3;++l){
    k_gemm64<<<(n_cell+63)/64, 256, 0, stream>>>(h_cur, conv_lin + l*4096,
        att_src + l*64, att_dst + l*64, hs, as_, ad_, n_cell);
    k_gat_agg<<<(n_cell+3)/4, 256, 0, stream>>>(rowptr, slot_src, slot_attr, alpha_ws,
        as_, ad_, hs, conv_bias + l*64, escal, l, h_cur, n_cell, 1);
  }

  // well GAT
  k_gemm64<<<(n_cell+63)/64, 256, 0, stream>>>(h_cur, wc_lin, wc_att_src, wc_att_dst,
      hs, as_, ad_, n_cell);
  k_well_ad<<<(n_well+3)/4, 256, 0, stream>>>(hw, wc_lin, wc_att_dst, ad_w, n_well);
  k_gat_agg<<<(n_well+3)/4, 256, 0, stream>>>(wrowptr, wslot, nullptr, walpha,
      as_, ad_w, hs, wc_bias, nullptr, 0, h_well, n_well, 0);

  // MLP head
  k_mlp<<<n_well, 128, 0, stream>>>(h_well, mlp_W1, mlp_b1, mlp_W2, mlp_b2, (float*)d_out, n_well);
}

// Round 3
// 837.910 us; speedup vs baseline: 1.2788x; 1.2788x over previous
//
#include <hip/hip_runtime.h>
#include <math.h>

__device__ __forceinline__ float wsum(float v){
  #pragma unroll
  for (int o=32;o;o>>=1) v += __shfl_xor(v,o);
  return v;
}

// out[n,64] = x[n,K] @ W[K,64] + b[64]
__global__ void k_embed(const float* __restrict__ x, const float* __restrict__ W,
                        const float* __restrict__ b, float* __restrict__ out,
                        int n, int K){
  int idx = blockIdx.x*blockDim.x + threadIdx.x;
  if (idx >= n*64) return;
  int node = idx >> 6, f = idx & 63;
  float acc = b[f];
  for (int k=0;k<K;++k) acc = fmaf(x[node*K+k], W[k*64+f], acc);
  out[idx] = acc;
}

// escal[l] = W_edge_row . (lin_edge_l @ att_e_l); escal[3+l] = b_edge . (...)
__global__ void k_edge_scalars(const float* __restrict__ lin_edge, // [3,64,64]
                               const float* __restrict__ att_e,   // [3,64]
                               const float* __restrict__ Wrow,    // [64]
                               const float* __restrict__ bemb,    // [64]
                               float* __restrict__ escal){
  int l = threadIdx.x >> 6, j = threadIdx.x & 63;
  float v = 0.f;
  for (int k=0;k<64;++k) v = fmaf(lin_edge[l*4096 + j*64 + k], att_e[l*64+k], v);
  float sv = wsum(Wrow[j]*v);
  float ov = wsum(bemb[j]*v);
  if (j==0){ escal[l]=sv; escal[3+l]=ov; }
}

__global__ void k_count(const int* __restrict__ dst, int* __restrict__ deg, int e){
  int i = blockIdx.x*blockDim.x + threadIdx.x;
  if (i<e) atomicAdd(&deg[dst[i]], 1);
}

__global__ void k_scan1(const int* __restrict__ deg, int* __restrict__ row1,
                        int* __restrict__ part, int n){
  __shared__ int sm[256];
  int i = blockIdx.x*256 + threadIdx.x;
  int v = (i<n) ? deg[i] : 0;
  sm[threadIdx.x] = v; __syncthreads();
  for (int o=1;o<256;o<<=1){
    int t = (threadIdx.x>= (unsigned)o) ? sm[threadIdx.x-o] : 0;
    __syncthreads();
    sm[threadIdx.x] += t; __syncthreads();
  }
  if (i<n) row1[i] = sm[threadIdx.x];
  if (threadIdx.x==255) part[blockIdx.x] = sm[255];
}

__global__ void k_scan2(int* __restrict__ part, int np){
  __shared__ int sm[1024];
  int t = threadIdx.x;
  sm[t] = (t<np) ? part[t] : 0; __syncthreads();
  for (int o=1;o<1024;o<<=1){
    int v = (t>=o) ? sm[t-o] : 0;
    __syncthreads();
    sm[t] += v; __syncthreads();
  }
  if (t<np) part[t] = (t==0) ? 0 : sm[t-1];
}

__global__ void k_scan3(int* __restrict__ rowptr, const int* __restrict__ part, int n){
  int i = blockIdx.x*256 + threadIdx.x;
  if (i<n) rowptr[i+1] += part[blockIdx.x];
  if (i==0) rowptr[0]=0;
}

__global__ void k_scan_single(const int* __restrict__ deg, int* __restrict__ rowptr, int n){
  __shared__ int sm[1024];
  int t = threadIdx.x;
  sm[t] = (t<n) ? deg[t] : 0; __syncthreads();
  for (int o=1;o<blockDim.x;o<<=1){
    int v = (t>=o)?sm[t-o]:0; __syncthreads();
    sm[t]+=v; __syncthreads();
  }
  if (t<n) rowptr[t+1]=sm[t];
  if (t==0) rowptr[0]=0;
}

__global__ void k_fill(const int* __restrict__ src, const int* __restrict__ dst,
                       const float* __restrict__ attr, const int* __restrict__ rowptr,
                       int* __restrict__ fillc, int* __restrict__ slot_src,
                       float* __restrict__ slot_attr, int e){
  int i = blockIdx.x*blockDim.x + threadIdx.x;
  if (i>=e) return;
  int d = dst[i];
  int pos = rowptr[d] + atomicAdd(&fillc[d], 1);
  slot_src[pos] = src[i];
  if (attr) slot_attr[pos] = attr[i];
}

// hs[n,64] = h[n,64] @ W[64,64]; as_[i]=hs[i].att_s; ad_[i]=hs[i].att_d
__global__ __launch_bounds__(256) void k_gemm64(
    const float* __restrict__ h, const float* __restrict__ W,
    const float* __restrict__ att_s, const float* __restrict__ att_d,
    float* __restrict__ hs, float* __restrict__ as_, float* __restrict__ ad_, int n){
  __shared__ float Ws[64*64];
  __shared__ float hT[64][68];
  int t = threadIdx.x;
  int n0 = blockIdx.x * 64;
  #pragma unroll
  for (int i=t;i<4096;i+=256) Ws[i] = W[i];
  for (int i=t;i<1024;i+=256){
    int node = i >> 4, k4 = (i & 15) << 2;
    int gn = n0 + node;
    float4 v = (gn < n) ? *(const float4*)&h[(size_t)gn*64 + k4] : make_float4(0,0,0,0);
    hT[k4+0][node]=v.x; hT[k4+1][node]=v.y; hT[k4+2][node]=v.z; hT[k4+3][node]=v.w;
  }
  __syncthreads();
  int tx = t & 15, ty = t >> 4;
  int f4 = tx*4;
  float acc[4][4] = {};
  for (int k=0;k<64;++k){
    float4 wv = *(const float4*)&Ws[k*64 + f4];
    float4 hv = *(const float4*)&hT[k][ty*4];
    float hvv[4] = {hv.x,hv.y,hv.z,hv.w};
    float wvv[4] = {wv.x,wv.y,wv.z,wv.w};
    #pragma unroll
    for (int i=0;i<4;++i)
      #pragma unroll
      for (int j=0;j<4;++j)
        acc[i][j] = fmaf(hvv[i], wvv[j], acc[i][j]);
  }
  float4 s4 = *(const float4*)&att_s[f4];
  float4 d4 = *(const float4*)&att_d[f4];
  #pragma unroll
  for (int i=0;i<4;++i){
    int gn = n0 + ty*4 + i;
    if (gn < n){
      *(float4*)&hs[(size_t)gn*64 + f4] = make_float4(acc[i][0],acc[i][1],acc[i][2],acc[i][3]);
      float sv = acc[i][0]*s4.x + acc[i][1]*s4.y + acc[i][2]*s4.z + acc[i][3]*s4.w;
      float dv = acc[i][0]*d4.x + acc[i][1]*d4.y + acc[i][2]*d4.z + acc[i][3]*d4.w;
      #pragma unroll
      for (int o=8;o;o>>=1){ sv += __shfl_xor(sv,o); dv += __shfl_xor(dv,o); }
      if (tx==0){ as_[gn]=sv; ad_[gn]=dv; }
    }
  }
}

// 16-lane group per dst node; lane g holds features [4g,4g+4). alpha in regs.
template<int NA, bool ATTR, bool RELU>
__global__ __launch_bounds__(256) void k_gat_agg2(
    const int* __restrict__ rowptr, const int* __restrict__ slot_src,
    const float* __restrict__ slot_attr, float* __restrict__ alpha_ws,
    const float* __restrict__ as_, const float* __restrict__ ad_,
    const float* __restrict__ hs, const float* __restrict__ bias,
    const float* __restrict__ escal, int l,
    float* __restrict__ out, int n){
  int t = threadIdx.x;
  int g = t & 15;
  int node = blockIdx.x*16 + (t >> 4);
  if (node >= n) return;
  int beg = rowptr[node], end = rowptr[node+1];
  float4 b4 = *(const float4*)&bias[g*4];
  if (end == beg){
    float4 r = b4;
    if (RELU){ r.x=fmaxf(r.x,0.f); r.y=fmaxf(r.y,0.f); r.z=fmaxf(r.z,0.f); r.w=fmaxf(r.w,0.f); }
    *(float4*)&out[(size_t)node*64 + g*4] = r;
    return;
  }
  float se = 0.f, oe = 0.f;
  if (ATTR){ se = escal[l]; oe = escal[3+l]; }
  float adn = ad_[node];
  float areg[NA]; int sreg[NA];
  float m = -1e30f;
  #pragma unroll
  for (int it=0; it<NA; ++it){
    int k = beg + it*16 + g;
    areg[it] = -1e30f; sreg[it] = 0;
    if (k < end){
      int s = slot_src[k];
      float a = as_[s] + adn;
      if (ATTR) a = fmaf(slot_attr[k], se, a) + oe;
      a = (a >= 0.f) ? a : 0.2f*a;
      areg[it] = a; sreg[it] = s;
      m = fmaxf(m, a);
    }
  }
  // overflow path (rare): degrees beyond NA*16
  for (int k = beg + NA*16 + g; k < end; k += 16){
    int s = slot_src[k];
    float a = as_[s] + adn;
    if (ATTR) a = fmaf(slot_attr[k], se, a) + oe;
    a = (a >= 0.f) ? a : 0.2f*a;
    alpha_ws[k] = a;
    m = fmaxf(m, a);
  }
  #pragma unroll
  for (int o=8;o;o>>=1) m = fmaxf(m, __shfl_xor(m, o, 16));

  float sum = 0.f;
  float4 acc = make_float4(0.f,0.f,0.f,0.f);
  #pragma unroll
  for (int it=0; it<NA; ++it){
    int base = beg + it*16;
    if (base < end){
      float p = (base + g < end) ? __expf(areg[it] - m) : 0.f;
      sum += p;
      int cnt = min(16, end - base);
      for (int j=0;j<cnt;++j){
        float pj = __shfl(p, j, 16);
        int   sj = __shfl(sreg[it], j, 16);
        float4 hv = *(const float4*)&hs[(size_t)sj*64 + g*4];
        acc.x = fmaf(hv.x, pj, acc.x);
        acc.y = fmaf(hv.y, pj, acc.y);
        acc.z = fmaf(hv.z, pj, acc.z);
        acc.w = fmaf(hv.w, pj, acc.w);
      }
    }
  }
  for (int base = beg + NA*16; base < end; base += 16){
    int k = base + g;
    float p = 0.f; int s = 0;
    if (k < end){ s = slot_src[k]; p = __expf(alpha_ws[k] - m); }
    sum += p;
    int cnt = min(16, end - base);
    for (int j=0;j<cnt;++j){
      float pj = __shfl(p, j, 16);
      int   sj = __shfl(s, j, 16);
      float4 hv = *(const float4*)&hs[(size_t)sj*64 + g*4];
      acc.x = fmaf(hv.x, pj, acc.x);
      acc.y = fmaf(hv.y, pj, acc.y);
      acc.z = fmaf(hv.z, pj, acc.z);
      acc.w = fmaf(hv.w, pj, acc.w);
    }
  }
  #pragma unroll
  for (int o=8;o;o>>=1) sum += __shfl_xor(sum, o, 16);
  float4 r;
  r.x = acc.x/sum + b4.x;
  r.y = acc.y/sum + b4.y;
  r.z = acc.z/sum + b4.z;
  r.w = acc.w/sum + b4.w;
  if (RELU){ r.x=fmaxf(r.x,0.f); r.y=fmaxf(r.y,0.f); r.z=fmaxf(r.z,0.f); r.w=fmaxf(r.w,0.f); }
  *(float4*)&out[(size_t)node*64 + g*4] = r;
}

// ad_w[w] = (h_w[w] @ wc_lin) . att_d
__global__ void k_well_ad(const float* __restrict__ hw, const float* __restrict__ W,
                          const float* __restrict__ att_d, float* __restrict__ ad_w, int n){
  int wv = threadIdx.x>>6, lane = threadIdx.x&63;
  int w = blockIdx.x*4 + wv;
  if (w>=n) return;
  float acc=0.f;
  for (int k=0;k<64;++k) acc = fmaf(hw[w*64+k], W[k*64+lane], acc);
  float v = wsum(acc * att_d[lane]);
  if (lane==0) ad_w[w]=v;
}

__global__ __launch_bounds__(128) void k_mlp(const float* __restrict__ h_well,
    const float* __restrict__ W1, const float* __restrict__ b1,
    const float* __restrict__ W2, const float* __restrict__ b2,
    float* __restrict__ out, int n){
  __shared__ float hr[64]; __shared__ float h1[64];
  int w = blockIdx.x, t = threadIdx.x;
  if (t<64) hr[t] = h_well[w*64+t];
  __syncthreads();
  if (t<64){
    float a = b1[t];
    for (int k=0;k<64;++k) a = fmaf(hr[k], W1[k*64+t], a);
    h1[t] = fmaxf(a, 0.f);
  }
  __syncthreads();
  if (t<75){
    float a = b2[t];
    for (int k=0;k<64;++k) a = fmaf(h1[k], W2[k*75+t], a);
    out[w*75+t] = a;
  }
}

extern "C" void kernel_launch(void* const* d_in, const int* in_sizes, int n_in,
                              void* d_out, int out_size, void* d_ws, size_t ws_size,
                              hipStream_t stream){
  const float* cell_x = (const float*)d_in[0];
  const float* well_x = (const float*)d_in[1];
  const float* eattr  = (const float*)d_in[2];
  const int*   cc_idx = (const int*)d_in[3];
  const int*   cw_idx = (const int*)d_in[4];
  const float* W_cell = (const float*)d_in[5];
  const float* b_cell = (const float*)d_in[6];
  const float* W_well = (const float*)d_in[7];
  const float* b_well = (const float*)d_in[8];
  const float* W_edge = (const float*)d_in[9];
  const float* b_edge = (const float*)d_in[10];
  const float* conv_lin = (const float*)d_in[11];
  const float* conv_lin_edge = (const float*)d_in[12];
  const float* att_src = (const float*)d_in[13];
  const float* att_dst = (const float*)d_in[14];
  const float* att_edge = (const float*)d_in[15];
  const float* conv_bias = (const float*)d_in[16];
  const float* wc_lin = (const float*)d_in[17];
  const float* wc_att_src = (const float*)d_in[18];
  const float* wc_att_dst = (const float*)d_in[19];
  const float* wc_bias = (const float*)d_in[20];
  const float* mlp_W1 = (const float*)d_in[21];
  const float* mlp_b1 = (const float*)d_in[22];
  const float* mlp_W2 = (const float*)d_in[23];
  const float* mlp_b2 = (const float*)d_in[24];

  int n_cell = in_sizes[0]/12;
  int n_well = in_sizes[1]/8;
  int e_cc = in_sizes[2];
  int e_cw = in_sizes[4]/2;

  const int* cc_src = cc_idx;
  const int* cc_dst = cc_idx + e_cc;
  const int* cw_src = cw_idx;
  const int* cw_dst = cw_idx + e_cw;

  char* p = (char*)d_ws;
  auto alloc = [&](size_t bytes)->void*{
    void* r = (void*)p;
    p += (bytes + 255) & ~(size_t)255;
    return r;
  };
  float* h_cur = (float*)alloc((size_t)n_cell*64*4);
  float* hs    = (float*)alloc((size_t)n_cell*64*4);
  float* as_   = (float*)alloc((size_t)n_cell*4);
  float* ad_   = (float*)alloc((size_t)n_cell*4);
  int* deg     = (int*)alloc((size_t)n_cell*4);
  int* fillc   = (int*)alloc((size_t)n_cell*4);
  int* rowptr  = (int*)alloc((size_t)(n_cell+1)*4);
  int* part    = (int*)alloc(1024*4);
  int* slot_src= (int*)alloc((size_t)e_cc*4);
  float* slot_attr = (float*)alloc((size_t)e_cc*4);
  float* alpha_ws  = (float*)alloc((size_t)e_cc*4);
  float* hw    = (float*)alloc((size_t)n_well*64*4);
  float* ad_w  = (float*)alloc((size_t)n_well*4);
  int* wdeg    = (int*)alloc((size_t)n_well*4);
  int* wfill   = (int*)alloc((size_t)n_well*4);
  int* wrowptr = (int*)alloc((size_t)(n_well+1)*4);
  int* wslot   = (int*)alloc((size_t)e_cw*4);
  float* walpha= (float*)alloc((size_t)e_cw*4);
  float* h_well= (float*)alloc((size_t)n_well*64*4);
  float* escal = (float*)alloc(64);

  hipMemsetAsync(deg, 0, (size_t)n_cell*4, stream);
  hipMemsetAsync(fillc, 0, (size_t)n_cell*4, stream);
  hipMemsetAsync(wdeg, 0, (size_t)n_well*4, stream);
  hipMemsetAsync(wfill, 0, (size_t)n_well*4, stream);

  // embeddings + edge scalars
  k_embed<<<(n_cell*64+255)/256, 256, 0, stream>>>(cell_x, W_cell, b_cell, h_cur, n_cell, 12);
  k_embed<<<(n_well*64+255)/256, 256, 0, stream>>>(well_x, W_well, b_well, hw, n_well, 8);
  k_edge_scalars<<<1, 192, 0, stream>>>(conv_lin_edge, att_edge, W_edge, b_edge, escal);

  // CSR (cells, by dst)
  k_count<<<(e_cc+255)/256, 256, 0, stream>>>(cc_dst, deg, e_cc);
  int nb = (n_cell+255)/256;
  k_scan1<<<nb, 256, 0, stream>>>(deg, rowptr+1, part, n_cell);
  k_scan2<<<1, 1024, 0, stream>>>(part, nb);
  k_scan3<<<nb, 256, 0, stream>>>(rowptr, part, n_cell);
  k_fill<<<(e_cc+255)/256, 256, 0, stream>>>(cc_src, cc_dst, eattr, rowptr, fillc, slot_src, slot_attr, e_cc);

  // CSR (wells)
  k_count<<<(e_cw+255)/256, 256, 0, stream>>>(cw_dst, wdeg, e_cw);
  k_scan_single<<<1, 512, 0, stream>>>(wdeg, wrowptr, n_well);
  k_fill<<<(e_cw+255)/256, 256, 0, stream>>>(cw_src, cw_dst, nullptr, wrowptr, wfill, wslot, nullptr, e_cw);

  // 3 GAT conv layers (cells)
  for (int l=0;l<3;++l){
    k_gemm64<<<(n_cell+63)/64, 256, 0, stream>>>(h_cur, conv_lin + l*4096,
        att_src + l*64, att_dst + l*64, hs, as_, ad_, n_cell);
    k_gat_agg2<4,true,true><<<(n_cell+15)/16, 256, 0, stream>>>(rowptr, slot_src, slot_attr,
        alpha_ws, as_, ad_, hs, conv_bias + l*64, escal, l, h_cur, n_cell);
  }

  // well GAT
  k_gemm64<<<(n_cell+63)/64, 256, 0, stream>>>(h_cur, wc_lin, wc_att_src, wc_att_dst,
      hs, as_, ad_, n_cell);
  k_well_ad<<<(n_well+3)/4, 256, 0, stream>>>(hw, wc_lin, wc_att_dst, ad_w, n_well);
  k_gat_agg2<16,false,false><<<(n_well+15)/16, 256, 0, stream>>>(wrowptr, wslot, nullptr,
      walpha, as_, ad_w, hs, wc_bias, nullptr, 0, h_well, n_well);

  // MLP head
  k_mlp<<<n_well, 128, 0, stream>>>(h_well, mlp_W1, mlp_b1, mlp_W2, mlp_b2, (float*)d_out, n_well);
}

// Round 4
// 683.125 us; speedup vs baseline: 1.5686x; 1.2266x over previous
//
#include <hip/hip_runtime.h>
#include <hip/hip_fp16.h>
#include <math.h>

__device__ __forceinline__ float wsum(float v){
  #pragma unroll
  for (int o=32;o;o>>=1) v += __shfl_xor(v,o);
  return v;
}

// out[n,64] = x[n,K] @ W[K,64] + b[64]
__global__ void k_embed(const float* __restrict__ x, const float* __restrict__ W,
                        const float* __restrict__ b, float* __restrict__ out,
                        int n, int K){
  int idx = blockIdx.x*blockDim.x + threadIdx.x;
  if (idx >= n*64) return;
  int node = idx >> 6, f = idx & 63;
  float acc = b[f];
  for (int k=0;k<K;++k) acc = fmaf(x[node*K+k], W[k*64+f], acc);
  out[idx] = acc;
}

// escal[l] = W_edge_row . (lin_edge_l @ att_e_l); escal[3+l] = b_edge . (...)
__global__ void k_edge_scalars(const float* __restrict__ lin_edge, // [3,64,64]
                               const float* __restrict__ att_e,   // [3,64]
                               const float* __restrict__ Wrow,    // [64]
                               const float* __restrict__ bemb,    // [64]
                               float* __restrict__ escal){
  int l = threadIdx.x >> 6, j = threadIdx.x & 63;
  float v = 0.f;
  for (int k=0;k<64;++k) v = fmaf(lin_edge[l*4096 + j*64 + k], att_e[l*64+k], v);
  float sv = wsum(Wrow[j]*v);
  float ov = wsum(bemb[j]*v);
  if (j==0){ escal[l]=sv; escal[3+l]=ov; }
}

// count degree AND record each edge's intra-bucket offset (atomic return value)
__global__ void k_count(const int* __restrict__ dst, int* __restrict__ deg,
                        int* __restrict__ off, int e){
  int i = blockIdx.x*blockDim.x + threadIdx.x;
  if (i<e) off[i] = atomicAdd(&deg[dst[i]], 1);
}

__global__ void k_scan1(const int* __restrict__ deg, int* __restrict__ row1,
                        int* __restrict__ part, int n){
  __shared__ int sm[256];
  int i = blockIdx.x*256 + threadIdx.x;
  int v = (i<n) ? deg[i] : 0;
  sm[threadIdx.x] = v; __syncthreads();
  for (int o=1;o<256;o<<=1){
    int t = (threadIdx.x>= (unsigned)o) ? sm[threadIdx.x-o] : 0;
    __syncthreads();
    sm[threadIdx.x] += t; __syncthreads();
  }
  if (i<n) row1[i] = sm[threadIdx.x];
  if (threadIdx.x==255) part[blockIdx.x] = sm[255];
}

__global__ void k_scan2(int* __restrict__ part, int np){
  __shared__ int sm[1024];
  int t = threadIdx.x;
  sm[t] = (t<np) ? part[t] : 0; __syncthreads();
  for (int o=1;o<1024;o<<=1){
    int v = (t>=o) ? sm[t-o] : 0;
    __syncthreads();
    sm[t] += v; __syncthreads();
  }
  if (t<np) part[t] = (t==0) ? 0 : sm[t-1];
}

__global__ void k_scan3(int* __restrict__ rowptr, const int* __restrict__ part, int n){
  int i = blockIdx.x*256 + threadIdx.x;
  if (i<n) rowptr[i+1] += part[blockIdx.x];
  if (i==0) rowptr[0]=0;
}

__global__ void k_scan_single(const int* __restrict__ deg, int* __restrict__ rowptr, int n){
  __shared__ int sm[1024];
  int t = threadIdx.x;
  sm[t] = (t<n) ? deg[t] : 0; __syncthreads();
  for (int o=1;o<blockDim.x;o<<=1){
    int v = (t>=o)?sm[t-o]:0; __syncthreads();
    sm[t]+=v; __syncthreads();
  }
  if (t<n) rowptr[t+1]=sm[t];
  if (t==0) rowptr[0]=0;
}

// cell fill: single 8B scatter {src, attr_bits}; no atomics
__global__ void k_fill_cc(const int* __restrict__ src, const int* __restrict__ dst,
                          const float* __restrict__ attr, const int* __restrict__ rowptr,
                          const int* __restrict__ off, int2* __restrict__ slot, int e){
  int i = blockIdx.x*blockDim.x + threadIdx.x;
  if (i>=e) return;
  int d = dst[i];
  int pos = rowptr[d] + off[i];
  slot[pos] = make_int2(src[i], __float_as_int(attr[i]));
}

// well fill: 4B scatter, no atomics
__global__ void k_fill_w(const int* __restrict__ src, const int* __restrict__ dst,
                         const int* __restrict__ rowptr, const int* __restrict__ off,
                         int* __restrict__ slot, int e){
  int i = blockIdx.x*blockDim.x + threadIdx.x;
  if (i>=e) return;
  int d = dst[i];
  slot[rowptr[d] + off[i]] = src[i];
}

// hs[n,64](fp16) = h[n,64] @ W[64,64]; as_[i]=hs[i].att_s; ad_[i]=hs[i].att_d (f32)
__global__ __launch_bounds__(256) void k_gemm64(
    const float* __restrict__ h, const float* __restrict__ W,
    const float* __restrict__ att_s, const float* __restrict__ att_d,
    __half* __restrict__ hs, float* __restrict__ as_, float* __restrict__ ad_, int n){
  __shared__ float Ws[64*64];
  __shared__ float hT[64][68];
  int t = threadIdx.x;
  int n0 = blockIdx.x * 64;
  #pragma unroll
  for (int i=t;i<4096;i+=256) Ws[i] = W[i];
  for (int i=t;i<1024;i+=256){
    int node = i >> 4, k4 = (i & 15) << 2;
    int gn = n0 + node;
    float4 v = (gn < n) ? *(const float4*)&h[(size_t)gn*64 + k4] : make_float4(0,0,0,0);
    hT[k4+0][node]=v.x; hT[k4+1][node]=v.y; hT[k4+2][node]=v.z; hT[k4+3][node]=v.w;
  }
  __syncthreads();
  int tx = t & 15, ty = t >> 4;
  int f4 = tx*4;
  float acc[4][4] = {};
  for (int k=0;k<64;++k){
    float4 wv = *(const float4*)&Ws[k*64 + f4];
    float4 hv = *(const float4*)&hT[k][ty*4];
    float hvv[4] = {hv.x,hv.y,hv.z,hv.w};
    float wvv[4] = {wv.x,wv.y,wv.z,wv.w};
    #pragma unroll
    for (int i=0;i<4;++i)
      #pragma unroll
      for (int j=0;j<4;++j)
        acc[i][j] = fmaf(hvv[i], wvv[j], acc[i][j]);
  }
  float4 s4 = *(const float4*)&att_s[f4];
  float4 d4 = *(const float4*)&att_d[f4];
  #pragma unroll
  for (int i=0;i<4;++i){
    int gn = n0 + ty*4 + i;
    if (gn < n){
      union { __half2 h2; unsigned u; } lo, hi;
      lo.h2 = __floats2half2_rn(acc[i][0], acc[i][1]);
      hi.h2 = __floats2half2_rn(acc[i][2], acc[i][3]);
      *(int2*)&hs[(size_t)gn*64 + f4] = make_int2((int)lo.u, (int)hi.u);
      float sv = acc[i][0]*s4.x + acc[i][1]*s4.y + acc[i][2]*s4.z + acc[i][3]*s4.w;
      float dv = acc[i][0]*d4.x + acc[i][1]*d4.y + acc[i][2]*d4.z + acc[i][3]*d4.w;
      #pragma unroll
      for (int o=8;o;o>>=1){ sv += __shfl_xor(sv,o); dv += __shfl_xor(dv,o); }
      if (tx==0){ as_[gn]=sv; ad_[gn]=dv; }
    }
  }
}

// 16-lane group per dst node; lane g holds features [4g,4g+4). alpha in regs.
// ATTR: slots are int2 {src, attr_bits}; else int src.
template<int NA, bool ATTR, bool RELU>
__global__ __launch_bounds__(256) void k_gat_agg2(
    const int* __restrict__ rowptr, const void* __restrict__ slots_v,
    float* __restrict__ alpha_ws,
    const float* __restrict__ as_, const float* __restrict__ ad_,
    const __half* __restrict__ hs, const float* __restrict__ bias,
    const float* __restrict__ escal, int l,
    float* __restrict__ out, int n){
  const int2* slot2 = (const int2*)slots_v;
  const int*  slot1 = (const int*)slots_v;
  int t = threadIdx.x;
  int g = t & 15;
  int node = blockIdx.x*16 + (t >> 4);
  if (node >= n) return;
  int beg = rowptr[node], end = rowptr[node+1];
  float4 b4 = *(const float4*)&bias[g*4];
  if (end == beg){
    float4 r = b4;
    if (RELU){ r.x=fmaxf(r.x,0.f); r.y=fmaxf(r.y,0.f); r.z=fmaxf(r.z,0.f); r.w=fmaxf(r.w,0.f); }
    *(float4*)&out[(size_t)node*64 + g*4] = r;
    return;
  }
  float se = 0.f, oe = 0.f;
  if (ATTR){ se = escal[l]; oe = escal[3+l]; }
  float adn = ad_[node];
  float areg[NA]; int sreg[NA];
  float m = -1e30f;
  #pragma unroll
  for (int it=0; it<NA; ++it){
    int k = beg + it*16 + g;
    areg[it] = -1e30f; sreg[it] = 0;
    if (k < end){
      int s; float a;
      if (ATTR){
        int2 sv = slot2[k];
        s = sv.x;
        a = as_[s] + adn;
        a = fmaf(__int_as_float(sv.y), se, a) + oe;
      } else {
        s = slot1[k];
        a = as_[s] + adn;
      }
      a = (a >= 0.f) ? a : 0.2f*a;
      areg[it] = a; sreg[it] = s;
      m = fmaxf(m, a);
    }
  }
  // overflow path (rare): degrees beyond NA*16
  for (int k = beg + NA*16 + g; k < end; k += 16){
    int s; float a;
    if (ATTR){
      int2 sv = slot2[k];
      s = sv.x;
      a = as_[s] + adn;
      a = fmaf(__int_as_float(sv.y), se, a) + oe;
    } else {
      s = slot1[k];
      a = as_[s] + adn;
    }
    a = (a >= 0.f) ? a : 0.2f*a;
    alpha_ws[k] = a;
    m = fmaxf(m, a);
  }
  #pragma unroll
  for (int o=8;o;o>>=1) m = fmaxf(m, __shfl_xor(m, o, 16));

  float sum = 0.f;
  float4 acc = make_float4(0.f,0.f,0.f,0.f);
  #pragma unroll
  for (int it=0; it<NA; ++it){
    int base = beg + it*16;
    if (base < end){
      float p = (base + g < end) ? __expf(areg[it] - m) : 0.f;
      sum += p;
      int cnt = min(16, end - base);
      for (int j=0;j<cnt;++j){
        float pj = __shfl(p, j, 16);
        int   sj = __shfl(sreg[it], j, 16);
        int2 hb = *(const int2*)&hs[(size_t)sj*64 + g*4];
        union { unsigned u; __half2 h2; } a0, a1; a0.u = (unsigned)hb.x; a1.u = (unsigned)hb.y;
        float2 f0 = __half22float2(a0.h2);
        float2 f1 = __half22float2(a1.h2);
        acc.x = fmaf(f0.x, pj, acc.x);
        acc.y = fmaf(f0.y, pj, acc.y);
        acc.z = fmaf(f1.x, pj, acc.z);
        acc.w = fmaf(f1.y, pj, acc.w);
      }
    }
  }
  for (int base = beg + NA*16; base < end; base += 16){
    int k = base + g;
    float p = 0.f; int s = 0;
    if (k < end){
      s = ATTR ? slot2[k].x : slot1[k];
      p = __expf(alpha_ws[k] - m);
    }
    sum += p;
    int cnt = min(16, end - base);
    for (int j=0;j<cnt;++j){
      float pj = __shfl(p, j, 16);
      int   sj = __shfl(s, j, 16);
      int2 hb = *(const int2*)&hs[(size_t)sj*64 + g*4];
      union { unsigned u; __half2 h2; } a0, a1; a0.u = (unsigned)hb.x; a1.u = (unsigned)hb.y;
      float2 f0 = __half22float2(a0.h2);
      float2 f1 = __half22float2(a1.h2);
      acc.x = fmaf(f0.x, pj, acc.x);
      acc.y = fmaf(f0.y, pj, acc.y);
      acc.z = fmaf(f1.x, pj, acc.z);
      acc.w = fmaf(f1.y, pj, acc.w);
    }
  }
  #pragma unroll
  for (int o=8;o;o>>=1) sum += __shfl_xor(sum, o, 16);
  float4 r;
  r.x = acc.x/sum + b4.x;
  r.y = acc.y/sum + b4.y;
  r.z = acc.z/sum + b4.z;
  r.w = acc.w/sum + b4.w;
  if (RELU){ r.x=fmaxf(r.x,0.f); r.y=fmaxf(r.y,0.f); r.z=fmaxf(r.z,0.f); r.w=fmaxf(r.w,0.f); }
  *(float4*)&out[(size_t)node*64 + g*4] = r;
}

// ad_w[w] = (h_w[w] @ wc_lin) . att_d
__global__ void k_well_ad(const float* __restrict__ hw, const float* __restrict__ W,
                          const float* __restrict__ att_d, float* __restrict__ ad_w, int n){
  int wv = threadIdx.x>>6, lane = threadIdx.x&63;
  int w = blockIdx.x*4 + wv;
  if (w>=n) return;
  float acc=0.f;
  for (int k=0;k<64;++k) acc = fmaf(hw[w*64+k], W[k*64+lane], acc);
  float v = wsum(acc * att_d[lane]);
  if (lane==0) ad_w[w]=v;
}

__global__ __launch_bounds__(128) void k_mlp(const float* __restrict__ h_well,
    const float* __restrict__ W1, const float* __restrict__ b1,
    const float* __restrict__ W2, const float* __restrict__ b2,
    float* __restrict__ out, int n){
  __shared__ float hr[64]; __shared__ float h1[64];
  int w = blockIdx.x, t = threadIdx.x;
  if (t<64) hr[t] = h_well[w*64+t];
  __syncthreads();
  if (t<64){
    float a = b1[t];
    for (int k=0;k<64;++k) a = fmaf(hr[k], W1[k*64+t], a);
    h1[t] = fmaxf(a, 0.f);
  }
  __syncthreads();
  if (t<75){
    float a = b2[t];
    for (int k=0;k<64;++k) a = fmaf(h1[k], W2[k*75+t], a);
    out[w*75+t] = a;
  }
}

extern "C" void kernel_launch(void* const* d_in, const int* in_sizes, int n_in,
                              void* d_out, int out_size, void* d_ws, size_t ws_size,
                              hipStream_t stream){
  const float* cell_x = (const float*)d_in[0];
  const float* well_x = (const float*)d_in[1];
  const float* eattr  = (const float*)d_in[2];
  const int*   cc_idx = (const int*)d_in[3];
  const int*   cw_idx = (const int*)d_in[4];
  const float* W_cell = (const float*)d_in[5];
  const float* b_cell = (const float*)d_in[6];
  const float* W_well = (const float*)d_in[7];
  const float* b_well = (const float*)d_in[8];
  const float* W_edge = (const float*)d_in[9];
  const float* b_edge = (const float*)d_in[10];
  const float* conv_lin = (const float*)d_in[11];
  const float* conv_lin_edge = (const float*)d_in[12];
  const float* att_src = (const float*)d_in[13];
  const float* att_dst = (const float*)d_in[14];
  const float* att_edge = (const float*)d_in[15];
  const float* conv_bias = (const float*)d_in[16];
  const float* wc_lin = (const float*)d_in[17];
  const float* wc_att_src = (const float*)d_in[18];
  const float* wc_att_dst = (const float*)d_in[19];
  const float* wc_bias = (const float*)d_in[20];
  const float* mlp_W1 = (const float*)d_in[21];
  const float* mlp_b1 = (const float*)d_in[22];
  const float* mlp_W2 = (const float*)d_in[23];
  const float* mlp_b2 = (const float*)d_in[24];

  int n_cell = in_sizes[0]/12;
  int n_well = in_sizes[1]/8;
  int e_cc = in_sizes[2];
  int e_cw = in_sizes[4]/2;

  const int* cc_src = cc_idx;
  const int* cc_dst = cc_idx + e_cc;
  const int* cw_src = cw_idx;
  const int* cw_dst = cw_idx + e_cw;

  char* p = (char*)d_ws;
  auto alloc = [&](size_t bytes)->void*{
    void* r = (void*)p;
    p += (bytes + 255) & ~(size_t)255;
    return r;
  };
  float* h_cur = (float*)alloc((size_t)n_cell*64*4);
  __half* hs   = (__half*)alloc((size_t)n_cell*64*2);
  float* as_   = (float*)alloc((size_t)n_cell*4);
  float* ad_   = (float*)alloc((size_t)n_cell*4);
  int* deg     = (int*)alloc((size_t)n_cell*4);
  int* rowptr  = (int*)alloc((size_t)(n_cell+1)*4);
  int* part    = (int*)alloc(1024*4);
  int* eoff    = (int*)alloc((size_t)e_cc*4);
  int2* slot2  = (int2*)alloc((size_t)e_cc*8);
  float* alpha_ws  = (float*)alloc((size_t)e_cc*4);
  float* hw    = (float*)alloc((size_t)n_well*64*4);
  float* ad_w  = (float*)alloc((size_t)n_well*4);
  int* wdeg    = (int*)alloc((size_t)n_well*4);
  int* wrowptr = (int*)alloc((size_t)(n_well+1)*4);
  int* woff    = (int*)alloc((size_t)e_cw*4);
  int* wslot   = (int*)alloc((size_t)e_cw*4);
  float* walpha= (float*)alloc((size_t)e_cw*4);
  float* h_well= (float*)alloc((size_t)n_well*64*4);
  float* escal = (float*)alloc(64);

  hipMemsetAsync(deg, 0, (size_t)n_cell*4, stream);
  hipMemsetAsync(wdeg, 0, (size_t)n_well*4, stream);

  // embeddings + edge scalars
  k_embed<<<(n_cell*64+255)/256, 256, 0, stream>>>(cell_x, W_cell, b_cell, h_cur, n_cell, 12);
  k_embed<<<(n_well*64+255)/256, 256, 0, stream>>>(well_x, W_well, b_well, hw, n_well, 8);
  k_edge_scalars<<<1, 192, 0, stream>>>(conv_lin_edge, att_edge, W_edge, b_edge, escal);

  // CSR (cells, by dst)
  k_count<<<(e_cc+255)/256, 256, 0, stream>>>(cc_dst, deg, eoff, e_cc);
  int nb = (n_cell+255)/256;
  k_scan1<<<nb, 256, 0, stream>>>(deg, rowptr+1, part, n_cell);
  k_scan2<<<1, 1024, 0, stream>>>(part, nb);
  k_scan3<<<nb, 256, 0, stream>>>(rowptr, part, n_cell);
  k_fill_cc<<<(e_cc+255)/256, 256, 0, stream>>>(cc_src, cc_dst, eattr, rowptr, eoff, slot2, e_cc);

  // CSR (wells)
  k_count<<<(e_cw+255)/256, 256, 0, stream>>>(cw_dst, wdeg, woff, e_cw);
  k_scan_single<<<1, 512, 0, stream>>>(wdeg, wrowptr, n_well);
  k_fill_w<<<(e_cw+255)/256, 256, 0, stream>>>(cw_src, cw_dst, wrowptr, woff, wslot, e_cw);

  // 3 GAT conv layers (cells)
  for (int l=0;l<3;++l){
    k_gemm64<<<(n_cell+63)/64, 256, 0, stream>>>(h_cur, conv_lin + l*4096,
        att_src + l*64, att_dst + l*64, hs, as_, ad_, n_cell);
    k_gat_agg2<4,true,true><<<(n_cell+15)/16, 256, 0, stream>>>(rowptr, slot2,
        alpha_ws, as_, ad_, hs, conv_bias + l*64, escal, l, h_cur, n_cell);
  }

  // well GAT
  k_gemm64<<<(n_cell+63)/64, 256, 0, stream>>>(h_cur, wc_lin, wc_att_src, wc_att_dst,
      hs, as_, ad_, n_cell);
  k_well_ad<<<(n_well+3)/4, 256, 0, stream>>>(hw, wc_lin, wc_att_dst, ad_w, n_well);
  k_gat_agg2<16,false,false><<<(n_well+15)/16, 256, 0, stream>>>(wrowptr, wslot,
      walpha, as_, ad_w, hs, wc_bias, nullptr, 0, h_well, n_well);

  // MLP head
  k_mlp<<<n_well, 128, 0, stream>>>(h_well, mlp_W1, mlp_b1, mlp_W2, mlp_b2, (float*)d_out, n_well);
}

// Round 5
// 604.423 us; speedup vs baseline: 1.7729x; 1.1302x over previous
//
#include <hip/hip_runtime.h>
#include <hip/hip_fp16.h>
#include <math.h>

__device__ __forceinline__ float wsum(float v){
  #pragma unroll
  for (int o=32;o;o>>=1) v += __shfl_xor(v,o);
  return v;
}

// escal[l] = W_edge_row . (lin_edge_l @ att_e_l); escal[3+l] = b_edge . (...)
__global__ void k_edge_scalars(const float* __restrict__ lin_edge, // [3,64,64]
                               const float* __restrict__ att_e,   // [3,64]
                               const float* __restrict__ Wrow,    // [64]
                               const float* __restrict__ bemb,    // [64]
                               float* __restrict__ escal){
  int l = threadIdx.x >> 6, j = threadIdx.x & 63;
  float v = 0.f;
  for (int k=0;k<64;++k) v = fmaf(lin_edge[l*4096 + j*64 + k], att_e[l*64+k], v);
  float sv = wsum(Wrow[j]*v);
  float ov = wsum(bemb[j]*v);
  if (j==0){ escal[l]=sv; escal[3+l]=ov; }
}

// Weff[12][64] = W_cell @ lin0 ; beff[64] = b_cell @ lin0
__global__ void k_prepA(const float* __restrict__ W_cell, const float* __restrict__ b_cell,
                        const float* __restrict__ lin0, float* __restrict__ weff){
  int t = threadIdx.x;
  for (int o=t; o<832; o+=256){
    float acc = 0.f;
    if (o < 768){
      int r = o >> 6, c2 = o & 63;
      for (int c=0;c<64;++c) acc = fmaf(W_cell[r*64+c], lin0[c*64+c2], acc);
    } else {
      int c2 = o - 768;
      for (int c=0;c<64;++c) acc = fmaf(b_cell[c], lin0[c*64+c2], acc);
    }
    weff[o] = acc;
  }
}

// wv8[r] = W_well_r . (wc_lin @ att_d); wprep[8] = b_well . (wc_lin @ att_d)
__global__ void k_prepB(const float* __restrict__ W_well, const float* __restrict__ b_well,
                        const float* __restrict__ wc_lin, const float* __restrict__ att_d,
                        float* __restrict__ wprep){
  __shared__ float tmp[64];
  int t = threadIdx.x;
  if (t < 64){
    float a = 0.f;
    for (int c=0;c<64;++c) a = fmaf(wc_lin[t*64+c], att_d[c], a);
    tmp[t] = a;
  }
  __syncthreads();
  if (t < 9){
    float a = 0.f;
    if (t < 8){ for (int k=0;k<64;++k) a = fmaf(W_well[t*64+k], tmp[k], a); }
    else      { for (int k=0;k<64;++k) a = fmaf(b_well[k],     tmp[k], a); }
    wprep[t] = a;
  }
}

// ad_w[w] = well_x[w] . wv8 + woff
__global__ void k_well_ad2(const float* __restrict__ well_x, const float* __restrict__ wprep,
                           float* __restrict__ ad_w, int n){
  int w = blockIdx.x*blockDim.x + threadIdx.x;
  if (w >= n) return;
  float a = wprep[8];
  #pragma unroll
  for (int r=0;r<8;++r) a = fmaf(well_x[w*8+r], wprep[r], a);
  ad_w[w] = a;
}

// count degree AND record each edge's intra-bucket offset (atomic return value)
__global__ void k_count(const int* __restrict__ dst, int* __restrict__ deg,
                        int* __restrict__ off, int e){
  int i = blockIdx.x*blockDim.x + threadIdx.x;
  if (i<e) off[i] = atomicAdd(&deg[dst[i]], 1);
}

__global__ void k_scan1(const int* __restrict__ deg, int* __restrict__ row1,
                        int* __restrict__ part, int n){
  __shared__ int sm[256];
  int i = blockIdx.x*256 + threadIdx.x;
  int v = (i<n) ? deg[i] : 0;
  sm[threadIdx.x] = v; __syncthreads();
  for (int o=1;o<256;o<<=1){
    int t = (threadIdx.x>= (unsigned)o) ? sm[threadIdx.x-o] : 0;
    __syncthreads();
    sm[threadIdx.x] += t; __syncthreads();
  }
  if (i<n) row1[i] = sm[threadIdx.x];
  if (threadIdx.x==255) part[blockIdx.x] = sm[255];
}

__global__ void k_scan2(int* __restrict__ part, int np){
  __shared__ int sm[1024];
  int t = threadIdx.x;
  sm[t] = (t<np) ? part[t] : 0; __syncthreads();
  for (int o=1;o<1024;o<<=1){
    int v = (t>=o) ? sm[t-o] : 0;
    __syncthreads();
    sm[t] += v; __syncthreads();
  }
  if (t<np) part[t] = (t==0) ? 0 : sm[t-1];
}

__global__ void k_scan3(int* __restrict__ rowptr, const int* __restrict__ part, int n){
  int i = blockIdx.x*256 + threadIdx.x;
  if (i<n) rowptr[i+1] += part[blockIdx.x];
  if (i==0) rowptr[0]=0;
}

__global__ void k_scan_single(const int* __restrict__ deg, int* __restrict__ rowptr, int n){
  __shared__ int sm[1024];
  int t = threadIdx.x;
  sm[t] = (t<n) ? deg[t] : 0; __syncthreads();
  for (int o=1;o<blockDim.x;o<<=1){
    int v = (t>=o)?sm[t-o]:0; __syncthreads();
    sm[t]+=v; __syncthreads();
  }
  if (t<n) rowptr[t+1]=sm[t];
  if (t==0) rowptr[0]=0;
}

// cell fill: single 8B scatter {src, attr_bits}; no atomics
__global__ void k_fill_cc(const int* __restrict__ src, const int* __restrict__ dst,
                          const float* __restrict__ attr, const int* __restrict__ rowptr,
                          const int* __restrict__ off, int2* __restrict__ slot, int e){
  int i = blockIdx.x*blockDim.x + threadIdx.x;
  if (i>=e) return;
  int d = dst[i];
  int pos = rowptr[d] + off[i];
  slot[pos] = make_int2(src[i], __float_as_int(attr[i]));
}

// well fill: 4B scatter, no atomics
__global__ void k_fill_w(const int* __restrict__ src, const int* __restrict__ dst,
                         const int* __restrict__ rowptr, const int* __restrict__ off,
                         int* __restrict__ slot, int e){
  int i = blockIdx.x*blockDim.x + threadIdx.x;
  if (i>=e) return;
  int d = dst[i];
  slot[rowptr[d] + off[i]] = src[i];
}

// hs[n,64](fp16) = h[n,64] @ W[64,64]; as_[i]=hs[i].att_s; ad_[i]=hs[i].att_d (f32)
__global__ __launch_bounds__(256) void k_gemm64(
    const float* __restrict__ h, const float* __restrict__ W,
    const float* __restrict__ att_s, const float* __restrict__ att_d,
    __half* __restrict__ hs, float* __restrict__ as_, float* __restrict__ ad_, int n){
  __shared__ float Ws[64*64];
  __shared__ float hT[64][68];
  int t = threadIdx.x;
  int n0 = blockIdx.x * 64;
  #pragma unroll
  for (int i=t;i<4096;i+=256) Ws[i] = W[i];
  for (int i=t;i<1024;i+=256){
    int node = i >> 4, k4 = (i & 15) << 2;
    int gn = n0 + node;
    float4 v = (gn < n) ? *(const float4*)&h[(size_t)gn*64 + k4] : make_float4(0,0,0,0);
    hT[k4+0][node]=v.x; hT[k4+1][node]=v.y; hT[k4+2][node]=v.z; hT[k4+3][node]=v.w;
  }
  __syncthreads();
  int tx = t & 15, ty = t >> 4;
  int f4 = tx*4;
  float acc[4][4] = {};
  for (int k=0;k<64;++k){
    float4 wv = *(const float4*)&Ws[k*64 + f4];
    float4 hv = *(const float4*)&hT[k][ty*4];
    float hvv[4] = {hv.x,hv.y,hv.z,hv.w};
    float wvv[4] = {wv.x,wv.y,wv.z,wv.w};
    #pragma unroll
    for (int i=0;i<4;++i)
      #pragma unroll
      for (int j=0;j<4;++j)
        acc[i][j] = fmaf(hvv[i], wvv[j], acc[i][j]);
  }
  float4 s4 = *(const float4*)&att_s[f4];
  float4 d4 = *(const float4*)&att_d[f4];
  #pragma unroll
  for (int i=0;i<4;++i){
    int gn = n0 + ty*4 + i;
    if (gn < n){
      union { __half2 h2; unsigned u; } lo, hi;
      lo.h2 = __floats2half2_rn(acc[i][0], acc[i][1]);
      hi.h2 = __floats2half2_rn(acc[i][2], acc[i][3]);
      *(int2*)&hs[(size_t)gn*64 + f4] = make_int2((int)lo.u, (int)hi.u);
      float sv = acc[i][0]*s4.x + acc[i][1]*s4.y + acc[i][2]*s4.z + acc[i][3]*s4.w;
      float dv = acc[i][0]*d4.x + acc[i][1]*d4.y + acc[i][2]*d4.z + acc[i][3]*d4.w;
      #pragma unroll
      for (int o=8;o;o>>=1){ sv += __shfl_xor(sv,o); dv += __shfl_xor(dv,o); }
      if (tx==0){ as_[gn]=sv; ad_[gn]=dv; }
    }
  }
}

// layer-0 fused: hs = x[n,12] @ Weff[12,64] + beff; epilogue as k_gemm64
__global__ __launch_bounds__(256) void k_gemm_l0(
    const float* __restrict__ x, const float* __restrict__ weff, // [832]: 12x64 + 64
    const float* __restrict__ att_s, const float* __restrict__ att_d,
    __half* __restrict__ hs, float* __restrict__ as_, float* __restrict__ ad_, int n){
  __shared__ float Ws[12*64];
  __shared__ float xT[12][68];
  int t = threadIdx.x;
  int n0 = blockIdx.x * 64;
  for (int i=t;i<768;i+=256){
    Ws[i] = weff[i];
    int node = i / 12, r = i - node*12;
    int gn = n0 + node;
    xT[r][node] = (gn < n) ? x[(size_t)gn*12 + r] : 0.f;
  }
  __syncthreads();
  int tx = t & 15, ty = t >> 4;
  int f4 = tx*4;
  float4 be = *(const float4*)&weff[768 + f4];
  float acc[4][4];
  #pragma unroll
  for (int i=0;i<4;++i){ acc[i][0]=be.x; acc[i][1]=be.y; acc[i][2]=be.z; acc[i][3]=be.w; }
  #pragma unroll
  for (int k=0;k<12;++k){
    float4 wv = *(const float4*)&Ws[k*64 + f4];
    float hvv[4];
    #pragma unroll
    for (int i=0;i<4;++i) hvv[i] = xT[k][ty*4+i];
    float wvv[4] = {wv.x,wv.y,wv.z,wv.w};
    #pragma unroll
    for (int i=0;i<4;++i)
      #pragma unroll
      for (int j=0;j<4;++j)
        acc[i][j] = fmaf(hvv[i], wvv[j], acc[i][j]);
  }
  float4 s4 = *(const float4*)&att_s[f4];
  float4 d4 = *(const float4*)&att_d[f4];
  #pragma unroll
  for (int i=0;i<4;++i){
    int gn = n0 + ty*4 + i;
    if (gn < n){
      union { __half2 h2; unsigned u; } lo, hi;
      lo.h2 = __floats2half2_rn(acc[i][0], acc[i][1]);
      hi.h2 = __floats2half2_rn(acc[i][2], acc[i][3]);
      *(int2*)&hs[(size_t)gn*64 + f4] = make_int2((int)lo.u, (int)hi.u);
      float sv = acc[i][0]*s4.x + acc[i][1]*s4.y + acc[i][2]*s4.z + acc[i][3]*s4.w;
      float dv = acc[i][0]*d4.x + acc[i][1]*d4.y + acc[i][2]*d4.z + acc[i][3]*d4.w;
      #pragma unroll
      for (int o=8;o;o>>=1){ sv += __shfl_xor(sv,o); dv += __shfl_xor(dv,o); }
      if (tx==0){ as_[gn]=sv; ad_[gn]=dv; }
    }
  }
}

// 16-lane group per dst node; lane g holds features [4g,4g+4). alpha in regs.
// ATTR: slots are int2 {src, attr_bits}; else int src.
template<int NA, bool ATTR, bool RELU>
__global__ __launch_bounds__(256) void k_gat_agg2(
    const int* __restrict__ rowptr, const void* __restrict__ slots_v,
    float* __restrict__ alpha_ws,
    const float* __restrict__ as_, const float* __restrict__ ad_,
    const __half* __restrict__ hs, const float* __restrict__ bias,
    const float* __restrict__ escal, int l,
    float* __restrict__ out, int n){
  const int2* slot2 = (const int2*)slots_v;
  const int*  slot1 = (const int*)slots_v;
  int t = threadIdx.x;
  int g = t & 15;
  int node = blockIdx.x*16 + (t >> 4);
  if (node >= n) return;
  int beg = rowptr[node], end = rowptr[node+1];
  float4 b4 = *(const float4*)&bias[g*4];
  if (end == beg){
    float4 r = b4;
    if (RELU){ r.x=fmaxf(r.x,0.f); r.y=fmaxf(r.y,0.f); r.z=fmaxf(r.z,0.f); r.w=fmaxf(r.w,0.f); }
    *(float4*)&out[(size_t)node*64 + g*4] = r;
    return;
  }
  float se = 0.f, oe = 0.f;
  if (ATTR){ se = escal[l]; oe = escal[3+l]; }
  float adn = ad_[node];
  float areg[NA]; int sreg[NA];
  float m = -1e30f;
  #pragma unroll
  for (int it=0; it<NA; ++it){
    int k = beg + it*16 + g;
    areg[it] = -1e30f; sreg[it] = 0;
    if (k < end){
      int s; float a;
      if (ATTR){
        int2 sv = slot2[k];
        s = sv.x;
        a = as_[s] + adn;
        a = fmaf(__int_as_float(sv.y), se, a) + oe;
      } else {
        s = slot1[k];
        a = as_[s] + adn;
      }
      a = (a >= 0.f) ? a : 0.2f*a;
      areg[it] = a; sreg[it] = s;
      m = fmaxf(m, a);
    }
  }
  // overflow path (rare): degrees beyond NA*16
  for (int k = beg + NA*16 + g; k < end; k += 16){
    int s; float a;
    if (ATTR){
      int2 sv = slot2[k];
      s = sv.x;
      a = as_[s] + adn;
      a = fmaf(__int_as_float(sv.y), se, a) + oe;
    } else {
      s = slot1[k];
      a = as_[s] + adn;
    }
    a = (a >= 0.f) ? a : 0.2f*a;
    alpha_ws[k] = a;
    m = fmaxf(m, a);
  }
  #pragma unroll
  for (int o=8;o;o>>=1) m = fmaxf(m, __shfl_xor(m, o, 16));

  float sum = 0.f;
  float4 acc = make_float4(0.f,0.f,0.f,0.f);
  #pragma unroll
  for (int it=0; it<NA; ++it){
    int base = beg + it*16;
    if (base < end){
      float p = (base + g < end) ? __expf(areg[it] - m) : 0.f;
      sum += p;
      int cnt = min(16, end - base);
      for (int j=0;j<cnt;++j){
        float pj = __shfl(p, j, 16);
        int   sj = __shfl(sreg[it], j, 16);
        int2 hb = *(const int2*)&hs[(size_t)sj*64 + g*4];
        union { unsigned u; __half2 h2; } a0, a1; a0.u = (unsigned)hb.x; a1.u = (unsigned)hb.y;
        float2 f0 = __half22float2(a0.h2);
        float2 f1 = __half22float2(a1.h2);
        acc.x = fmaf(f0.x, pj, acc.x);
        acc.y = fmaf(f0.y, pj, acc.y);
        acc.z = fmaf(f1.x, pj, acc.z);
        acc.w = fmaf(f1.y, pj, acc.w);
      }
    }
  }
  for (int base = beg + NA*16; base < end; base += 16){
    int k = base + g;
    float p = 0.f; int s = 0;
    if (k < end){
      s = ATTR ? slot2[k].x : slot1[k];
      p = __expf(alpha_ws[k] - m);
    }
    sum += p;
    int cnt = min(16, end - base);
    for (int j=0;j<cnt;++j){
      float pj = __shfl(p, j, 16);
      int   sj = __shfl(s, j, 16);
      int2 hb = *(const int2*)&hs[(size_t)sj*64 + g*4];
      union { unsigned u; __half2 h2; } a0, a1; a0.u = (unsigned)hb.x; a1.u = (unsigned)hb.y;
      float2 f0 = __half22float2(a0.h2);
      float2 f1 = __half22float2(a1.h2);
      acc.x = fmaf(f0.x, pj, acc.x);
      acc.y = fmaf(f0.y, pj, acc.y);
      acc.z = fmaf(f1.x, pj, acc.z);
      acc.w = fmaf(f1.y, pj, acc.w);
    }
  }
  #pragma unroll
  for (int o=8;o;o>>=1) sum += __shfl_xor(sum, o, 16);
  float4 r;
  r.x = acc.x/sum + b4.x;
  r.y = acc.y/sum + b4.y;
  r.z = acc.z/sum + b4.z;
  r.w = acc.w/sum + b4.w;
  if (RELU){ r.x=fmaxf(r.x,0.f); r.y=fmaxf(r.y,0.f); r.z=fmaxf(r.z,0.f); r.w=fmaxf(r.w,0.f); }
  *(float4*)&out[(size_t)node*64 + g*4] = r;
}

__global__ __launch_bounds__(128) void k_mlp(const float* __restrict__ h_well,
    const float* __restrict__ W1, const float* __restrict__ b1,
    const float* __restrict__ W2, const float* __restrict__ b2,
    float* __restrict__ out, int n){
  __shared__ float hr[64]; __shared__ float h1[64];
  int w = blockIdx.x, t = threadIdx.x;
  if (t<64) hr[t] = h_well[w*64+t];
  __syncthreads();
  if (t<64){
    float a = b1[t];
    for (int k=0;k<64;++k) a = fmaf(hr[k], W1[k*64+t], a);
    h1[t] = fmaxf(a, 0.f);
  }
  __syncthreads();
  if (t<75){
    float a = b2[t];
    for (int k=0;k<64;++k) a = fmaf(h1[k], W2[k*75+t], a);
    out[w*75+t] = a;
  }
}

extern "C" void kernel_launch(void* const* d_in, const int* in_sizes, int n_in,
                              void* d_out, int out_size, void* d_ws, size_t ws_size,
                              hipStream_t stream){
  const float* cell_x = (const float*)d_in[0];
  const float* well_x = (const float*)d_in[1];
  const float* eattr  = (const float*)d_in[2];
  const int*   cc_idx = (const int*)d_in[3];
  const int*   cw_idx = (const int*)d_in[4];
  const float* W_cell = (const float*)d_in[5];
  const float* b_cell = (const float*)d_in[6];
  const float* W_well = (const float*)d_in[7];
  const float* b_well = (const float*)d_in[8];
  const float* W_edge = (const float*)d_in[9];
  const float* b_edge = (const float*)d_in[10];
  const float* conv_lin = (const float*)d_in[11];
  const float* conv_lin_edge = (const float*)d_in[12];
  const float* att_src = (const float*)d_in[13];
  const float* att_dst = (const float*)d_in[14];
  const float* att_edge = (const float*)d_in[15];
  const float* conv_bias = (const float*)d_in[16];
  const float* wc_lin = (const float*)d_in[17];
  const float* wc_att_src = (const float*)d_in[18];
  const float* wc_att_dst = (const float*)d_in[19];
  const float* wc_bias = (const float*)d_in[20];
  const float* mlp_W1 = (const float*)d_in[21];
  const float* mlp_b1 = (const float*)d_in[22];
  const float* mlp_W2 = (const float*)d_in[23];
  const float* mlp_b2 = (const float*)d_in[24];

  int n_cell = in_sizes[0]/12;
  int n_well = in_sizes[1]/8;
  int e_cc = in_sizes[2];
  int e_cw = in_sizes[4]/2;

  const int* cc_src = cc_idx;
  const int* cc_dst = cc_idx + e_cc;
  const int* cw_src = cw_idx;
  const int* cw_dst = cw_idx + e_cw;

  char* p = (char*)d_ws;
  auto alloc = [&](size_t bytes)->void*{
    void* r = (void*)p;
    p += (bytes + 255) & ~(size_t)255;
    return r;
  };
  float* h_cur = (float*)alloc((size_t)n_cell*64*4);
  __half* hs   = (__half*)alloc((size_t)n_cell*64*2);
  float* as_   = (float*)alloc((size_t)n_cell*4);
  float* ad_   = (float*)alloc((size_t)n_cell*4);
  int* deg     = (int*)alloc((size_t)n_cell*4);
  int* rowptr  = (int*)alloc((size_t)(n_cell+1)*4);
  int* part    = (int*)alloc(1024*4);
  int* eoff    = (int*)alloc((size_t)e_cc*4);
  int2* slot2  = (int2*)alloc((size_t)e_cc*8);
  float* alpha_ws  = (float*)alloc((size_t)e_cc*4);
  float* ad_w  = (float*)alloc((size_t)n_well*4);
  int* wdeg    = (int*)alloc((size_t)n_well*4);
  int* wrowptr = (int*)alloc((size_t)(n_well+1)*4);
  int* woff    = (int*)alloc((size_t)e_cw*4);
  int* wslot   = (int*)alloc((size_t)e_cw*4);
  float* walpha= (float*)alloc((size_t)e_cw*4);
  float* h_well= (float*)alloc((size_t)n_well*64*4);
  float* escal = (float*)alloc(64);
  float* weff  = (float*)alloc(832*4);
  float* wprep = (float*)alloc(16*4);

  hipMemsetAsync(deg, 0, (size_t)n_cell*4, stream);
  hipMemsetAsync(wdeg, 0, (size_t)n_well*4, stream);

  // precomputed small tensors
  k_edge_scalars<<<1, 192, 0, stream>>>(conv_lin_edge, att_edge, W_edge, b_edge, escal);
  k_prepA<<<1, 256, 0, stream>>>(W_cell, b_cell, conv_lin, weff);
  k_prepB<<<1, 128, 0, stream>>>(W_well, b_well, wc_lin, wc_att_dst, wprep);

  // CSR (cells, by dst)
  k_count<<<(e_cc+255)/256, 256, 0, stream>>>(cc_dst, deg, eoff, e_cc);
  int nb = (n_cell+255)/256;
  k_scan1<<<nb, 256, 0, stream>>>(deg, rowptr+1, part, n_cell);
  k_scan2<<<1, 1024, 0, stream>>>(part, nb);
  k_scan3<<<nb, 256, 0, stream>>>(rowptr, part, n_cell);
  k_fill_cc<<<(e_cc+255)/256, 256, 0, stream>>>(cc_src, cc_dst, eattr, rowptr, eoff, slot2, e_cc);

  // CSR (wells)
  k_count<<<(e_cw+255)/256, 256, 0, stream>>>(cw_dst, wdeg, woff, e_cw);
  k_scan_single<<<1, 512, 0, stream>>>(wdeg, wrowptr, n_well);
  k_fill_w<<<(e_cw+255)/256, 256, 0, stream>>>(cw_src, cw_dst, wrowptr, woff, wslot, e_cw);

  // layer 0: fused embed+gemm reading cell_x directly
  k_gemm_l0<<<(n_cell+63)/64, 256, 0, stream>>>(cell_x, weff,
      att_src, att_dst, hs, as_, ad_, n_cell);
  k_gat_agg2<4,true,true><<<(n_cell+15)/16, 256, 0, stream>>>(rowptr, slot2,
      alpha_ws, as_, ad_, hs, conv_bias, escal, 0, h_cur, n_cell);

  // layers 1,2
  for (int l=1;l<3;++l){
    k_gemm64<<<(n_cell+63)/64, 256, 0, stream>>>(h_cur, conv_lin + l*4096,
        att_src + l*64, att_dst + l*64, hs, as_, ad_, n_cell);
    k_gat_agg2<4,true,true><<<(n_cell+15)/16, 256, 0, stream>>>(rowptr, slot2,
        alpha_ws, as_, ad_, hs, conv_bias + l*64, escal, l, h_cur, n_cell);
  }

  // well GAT
  k_gemm64<<<(n_cell+63)/64, 256, 0, stream>>>(h_cur, wc_lin, wc_att_src, wc_att_dst,
      hs, as_, ad_, n_cell);
  k_well_ad2<<<(n_well+255)/256, 256, 0, stream>>>(well_x, wprep, ad_w, n_well);
  k_gat_agg2<16,false,false><<<(n_well+15)/16, 256, 0, stream>>>(wrowptr, wslot,
      walpha, as_, ad_w, hs, wc_bias, nullptr, 0, h_well, n_well);

  // MLP head
  k_mlp<<<n_well, 128, 0, stream>>>(h_well, mlp_W1, mlp_b1, mlp_W2, mlp_b2, (float*)d_out, n_well);
}